// Round 9
// baseline (991.017 us; speedup 1.0000x reference)
//
#include <hip/hip_runtime.h>
#include <math.h>

constexpr int K_IN  = 1433;
constexpr int HID   = 16;
constexpr int NCLS  = 7;
constexpr int BLK   = 256;
constexpr int CHUNK = 256;   // K-chunk of W1 staged in LDS
constexpr int NB    = 256;   // coarse buckets: bucket = col >> 9
constexpr int NBLKA = 1024;  // pass-A blocks

// R9 PROBE: k_gemm1 launched 3x (2 redundant idempotent repeats).
// dur = base + 2*C_gemm1. Build micro-opts: packed 26-bit sorted entries,
// scanB folded into placeA/bucketB as in-block 256-scans.

__device__ inline float4 wave_reduce4(float4 v) {
#pragma unroll
  for (int off = 32; off > 0; off >>= 1) {
    v.x += __shfl_xor(v.x, off);
    v.y += __shfl_xor(v.y, off);
    v.z += __shfl_xor(v.z, off);
    v.w += __shfl_xor(v.w, off);
  }
  return v;
}

// exclusive scan over 256 values held one-per-thread (256-thread block)
__device__ inline int block_excl_scan256(int v, int* wsum) {
  const int lane = threadIdx.x & 63, wid = threadIdx.x >> 6;
  int s = v;
#pragma unroll
  for (int off = 1; off < 64; off <<= 1) {
    int t = __shfl_up(s, off);
    if (lane >= off) s += t;
  }
  if (lane == 63) wsum[wid] = s;
  __syncthreads();
  int woff = 0;
#pragma unroll
  for (int k = 0; k < 4; ++k) woff += (k < wid) ? wsum[k] : 0;
  return woff + s - v;
}

// ---- atomic-free CSR build (two-level LDS-histogram counting sort) -----

// A1: per-block coarse histogram (LDS atomics only)
__global__ __launch_bounds__(256) void k_histA(const int* __restrict__ col,
                                               int* __restrict__ gHist, int nE) {
  __shared__ int h[NB];
  h[threadIdx.x] = 0;
  __syncthreads();
  const int ch = (nE + NBLKA - 1) / NBLKA;
  const int e0 = blockIdx.x * ch;
  const int e1 = min(e0 + ch, nE);
  for (int e = e0 + threadIdx.x; e < e1; e += 256) atomicAdd(&h[col[e] >> 9], 1);
  __syncthreads();
  gHist[threadIdx.x * NBLKA + blockIdx.x] = h[threadIdx.x];  // bucket-major
}

// A2: per-bucket exclusive scan across the 1024 block-counts (in place); total -> bTot
__global__ __launch_bounds__(256) void k_scanA(int* __restrict__ gHist,
                                               int* __restrict__ bTot) {
  __shared__ int wsum[4];
  const int b = blockIdx.x, t = threadIdx.x;
  int4* p = (int4*)(gHist + (size_t)b * NBLKA);
  int4 c = p[t];
  const int tsum = c.x + c.y + c.z + c.w;
  const int base = block_excl_scan256(tsum, wsum);
  int4 o; o.x = base; o.y = base + c.x; o.z = o.y + c.y; o.w = o.z + c.z;
  p[t] = o;
  if (t == 255) bTot[b] = base + tsum;
}

// A3: place packed (fine9<<17 | row) into coarse-sorted order
__global__ __launch_bounds__(256) void k_placeA(const int* __restrict__ row,
                                                const int* __restrict__ col,
                                                const int* __restrict__ gHist,
                                                const int* __restrict__ bTot,
                                                int* __restrict__ sorted, int nE) {
  __shared__ int cur[NB];
  __shared__ int wsum[4];
  const int t = threadIdx.x;
  const int excl = block_excl_scan256(bTot[t], wsum);   // bBase on the fly
  cur[t] = excl + gHist[t * NBLKA + blockIdx.x];
  __syncthreads();
  const int ch = (nE + NBLKA - 1) / NBLKA;
  const int e0 = blockIdx.x * ch;
  const int e1 = min(e0 + ch, nE);
  for (int e = e0 + t; e < e1; e += 256) {
    const int c = col[e];
    const int p = atomicAdd(&cur[c >> 9], 1);           // LDS atomic
    sorted[p] = ((c & 511) << 17) | row[e];             // 26-bit pack
  }
}

// B: one block per coarse bucket — fine histogram[512], scan, CSR outputs, place
__global__ __launch_bounds__(256) void k_bucketB(const int* __restrict__ sorted,
                                                 const int* __restrict__ bTot,
                                                 int* __restrict__ cnt,
                                                 int* __restrict__ start,
                                                 float* __restrict__ dinv,
                                                 int* __restrict__ rows, int n) {
  __shared__ int h[512];
  __shared__ int ls[512];
  __shared__ int sBase[NB];
  __shared__ int wsum[4];
  const int b = blockIdx.x, t = threadIdx.x;
  const int lane = t & 63, wid = t >> 6;
  h[t] = 0; h[t + 256] = 0;
  sBase[t] = block_excl_scan256(bTot[t], wsum);         // bBase on the fly
  __syncthreads();
  const int s0 = sBase[b];
  const int s1 = (b < 255) ? sBase[b + 1] : s0 + bTot[b];
  for (int e = s0 + t; e < s1; e += 256) atomicAdd(&h[(sorted[e] >> 17) & 511], 1);
  __syncthreads();
  // block exclusive scan of h[512], 2 contiguous elems/thread
  const int c0 = h[2 * t], c1 = h[2 * t + 1];
  const int tsum = c0 + c1;
  int s = tsum;
#pragma unroll
  for (int off = 1; off < 64; off <<= 1) { int v = __shfl_up(s, off); if (lane >= off) s += v; }
  if (lane == 63) wsum[wid] = s;
  __syncthreads();
  int woff = 0;
#pragma unroll
  for (int k = 0; k < 4; ++k) woff += (k < wid) ? wsum[k] : 0;
  const int base = woff + s - tsum;
  ls[2 * t] = base;
  ls[2 * t + 1] = base + c0;
  const int gc0 = b * 512 + 2 * t;
  if (gc0 < n) {
    cnt[gc0] = c0; start[gc0] = s0 + base;
    dinv[gc0] = rsqrtf((float)(c0 + 1));
  }
  if (gc0 + 1 < n) {
    cnt[gc0 + 1] = c1; start[gc0 + 1] = s0 + base + c0;
    dinv[gc0 + 1] = rsqrtf((float)(c1 + 1));
  }
  __syncthreads();
  for (int e = s0 + t; e < s1; e += 256) {
    const int rc = sorted[e];
    const int p = atomicAdd(&ls[(rc >> 17) & 511], 1);  // LDS cursor
    rows[s0 + p] = rc & 0x1FFFF;
  }
}

// ---- layer compute -----------------------------------------------------

// h1s = dinv * (x @ W1 + b1). 8 rows/block, 2 rows/wave.
__global__ __launch_bounds__(BLK) void k_gemm1(const float* __restrict__ x,
                                               const float* __restrict__ W1,
                                               const float* __restrict__ b1,
                                               const float* __restrict__ dinv,
                                               float* __restrict__ h1s, int n) {
  __shared__ float4 ws4[CHUNK * 5];
  const int lane = threadIdx.x & 63;
  const int wave = threadIdx.x >> 6;
  const int r0 = blockIdx.x * 8 + wave * 2;
  const int r1 = r0 + 1;
  const bool v0 = r0 < n, v1 = r1 < n;
  const float* xr0 = x + (size_t)r0 * K_IN;
  const float* xr1 = x + (size_t)r1 * K_IN;
  float4 a0[4] = {};
  float4 a1[4] = {};

  for (int kc = 0; kc < K_IN; kc += CHUNK) {
    const int kcnt = min(CHUNK, K_IN - kc);
    for (int t = threadIdx.x; t < kcnt * 4; t += BLK) {
      const int kk = t >> 2, j = t & 3;
      ws4[kk * 5 + j] = ((const float4*)W1)[(size_t)(kc + kk) * 4 + j];
    }
    __syncthreads();
#pragma unroll
    for (int j = 0; j < 4; ++j) {
      const int k = kc + j * 64 + lane;
      if (k < K_IN) {
        const int kl = k - kc;
        const float xv0 = v0 ? xr0[k] : 0.0f;
        const float xv1 = v1 ? xr1[k] : 0.0f;
#pragma unroll
        for (int f = 0; f < 4; ++f) {
          const float4 w = ws4[kl * 5 + f];
          a0[f].x = fmaf(xv0, w.x, a0[f].x);
          a0[f].y = fmaf(xv0, w.y, a0[f].y);
          a0[f].z = fmaf(xv0, w.z, a0[f].z);
          a0[f].w = fmaf(xv0, w.w, a0[f].w);
          a1[f].x = fmaf(xv1, w.x, a1[f].x);
          a1[f].y = fmaf(xv1, w.y, a1[f].y);
          a1[f].z = fmaf(xv1, w.z, a1[f].z);
          a1[f].w = fmaf(xv1, w.w, a1[f].w);
        }
      }
    }
    __syncthreads();
  }

#pragma unroll
  for (int f = 0; f < 4; ++f) {
    a0[f] = wave_reduce4(a0[f]);
    a1[f] = wave_reduce4(a1[f]);
  }
  if (lane == 0) {
    const float4* b14 = (const float4*)b1;
    const float d0 = v0 ? dinv[r0] : 0.0f;
    const float d1 = v1 ? dinv[r1] : 0.0f;
    float4* o0 = (float4*)(h1s + (size_t)r0 * HID);
    float4* o1 = (float4*)(h1s + (size_t)r1 * HID);
#pragma unroll
    for (int f = 0; f < 4; ++f) {
      const float4 bb = b14[f];
      if (v0) o0[f] = make_float4(d0 * (a0[f].x + bb.x), d0 * (a0[f].y + bb.y),
                                  d0 * (a0[f].z + bb.z), d0 * (a0[f].w + bb.w));
      if (v1) o1[f] = make_float4(d1 * (a1[f].x + bb.x), d1 * (a1[f].y + bb.y),
                                  d1 * (a1[f].z + bb.z), d1 * (a1[f].w + bb.w));
    }
  }
}

// Fused gather-1 + gemm2: one wave per node (16 feats x 4 edge-groups).
__global__ __launch_bounds__(BLK) void k_gather1g2(const int* __restrict__ rows,
                                                   const int* __restrict__ start,
                                                   const int* __restrict__ cnt,
                                                   const float* __restrict__ dinv,
                                                   const float* __restrict__ h1s,
                                                   const float* __restrict__ W2,
                                                   const float* __restrict__ b2,
                                                   float* __restrict__ h2s, int n) {
  __shared__ float w2s[HID * NCLS];
  __shared__ float b2s[NCLS];
  if (threadIdx.x < HID * NCLS) w2s[threadIdx.x] = W2[threadIdx.x];
  if (threadIdx.x < NCLS) b2s[threadIdx.x] = b2[threadIdx.x];
  __syncthreads();
  const int node = blockIdx.x * 4 + (threadIdx.x >> 6);
  const int lane = threadIdx.x & 63;
  const int f = lane & 15;   // feature
  const int g = lane >> 4;   // edge subgroup
  if (node >= n) return;
  const float dc = dinv[node];
  float acc = (g == 0) ? h1s[(size_t)node * HID + f] : 0.0f;  // self loop
  const int m = cnt[node];
  const int* bp = rows + start[node];
  int q = g;
  for (; q + 4 < m; q += 8) {
    const int r0 = bp[q], r1 = bp[q + 4];
    acc += h1s[(size_t)r0 * HID + f];
    acc += h1s[(size_t)r1 * HID + f];
  }
  if (q < m) acc += h1s[(size_t)bp[q] * HID + f];
  acc += __shfl_xor(acc, 16);
  acc += __shfl_xor(acc, 32);
  acc = fmaxf(dc * acc, 0.0f);  // normalize + relu
  float sj[NCLS];
#pragma unroll
  for (int j = 0; j < NCLS; ++j) sj[j] = acc * w2s[f * NCLS + j];
#pragma unroll
  for (int off = 1; off < 16; off <<= 1)
#pragma unroll
    for (int j = 0; j < NCLS; ++j) sj[j] += __shfl_xor(sj[j], off);
  if (g == 0 && f < NCLS) {
    float v = sj[0];
#pragma unroll
    for (int j = 1; j < NCLS; ++j) if (f == j) v = sj[j];
    h2s[(size_t)node * NCLS + f] = dc * (v + b2s[f]);
  }
}

// gather-2 + log_softmax: one wave per node (8 feat-lanes x 8 edge-groups)
__global__ __launch_bounds__(BLK) void k_gather2(const int* __restrict__ rows,
                                                 const int* __restrict__ start,
                                                 const int* __restrict__ cnt,
                                                 const float* __restrict__ dinv,
                                                 const float* __restrict__ h2s,
                                                 float* __restrict__ out, int n) {
  const int node = blockIdx.x * 4 + (threadIdx.x >> 6);
  const int lane = threadIdx.x & 63;
  const int f = lane & 7;    // feature (f<7 active)
  const int g = lane >> 3;   // edge subgroup
  if (node >= n) return;
  const float dc = dinv[node];
  float acc = (g == 0) ? h2s[(size_t)node * NCLS + f] : 0.0f;  // self loop
  const int m = cnt[node];
  const int* bp = rows + start[node];
  int q = g;
  for (; q + 8 < m; q += 16) {
    const int r0 = bp[q], r1 = bp[q + 8];
    acc += h2s[(size_t)r0 * NCLS + f];
    acc += h2s[(size_t)r1 * NCLS + f];
  }
  if (q < m) acc += h2s[(size_t)bp[q] * NCLS + f];
  acc += __shfl_xor(acc, 8);
  acc += __shfl_xor(acc, 16);
  acc += __shfl_xor(acc, 32);
  const bool act = f < NCLS;
  const float t = fmaxf(dc * acc, 0.0f);  // normalize + relu
  float tm = act ? t : -1e30f;
#pragma unroll
  for (int off = 1; off < 8; off <<= 1) tm = fmaxf(tm, __shfl_xor(tm, off, 8));
  float se = act ? __expf(t - tm) : 0.0f;
#pragma unroll
  for (int off = 1; off < 8; off <<= 1) se += __shfl_xor(se, off, 8);
  const float lse = tm + __logf(se);
  if (g == 0 && act) out[(size_t)node * NCLS + f] = t - lse;
}

extern "C" void kernel_launch(void* const* d_in, const int* in_sizes, int n_in,
                              void* d_out, int out_size, void* d_ws, size_t ws_size,
                              hipStream_t stream) {
  const float* x  = (const float*)d_in[0];
  const float* W1 = (const float*)d_in[1];
  const float* b1 = (const float*)d_in[2];
  const float* W2 = (const float*)d_in[3];
  const float* b2 = (const float*)d_in[4];
  const int*   ei = (const int*)d_in[5];

  const int n  = in_sizes[0] / K_IN;       // 100000
  const int nE = in_sizes[5] / 2;          // 3200000
  const int* row = ei;                     // edge_index[0] (source)
  const int* col = ei + nE;                // edge_index[1] (target)

  // workspace layout, 16B-aligned blocks
  char* w = (char*)d_ws;
  size_t off = 0;
  auto alloc = [&](size_t elems) {
    void* p = w + off;
    off += ((elems * 4 + 15) & ~(size_t)15);
    return p;
  };
  int*   cnt    = (int*)alloc(n);
  int*   start  = (int*)alloc(n);
  float* dinv   = (float*)alloc(n);
  float* h1s    = (float*)alloc((size_t)n * HID);
  float* h2s    = (float*)alloc((size_t)n * NCLS + 16);  // +pad for f==7 reads
  int*   gHist  = (int*)alloc((size_t)NB * NBLKA);
  int*   bTot   = (int*)alloc(NB);
  int*   sorted = (int*)alloc(nE);
  int*   rows   = (int*)alloc(nE);

  const int gG1 = (n + 7) / 8;            // gemm1: 8 rows/block
  const int gWN = (n + 3) / 4;            // wave-per-node kernels: 4 nodes/block

  // atomic-free CSR build
  k_histA<<<NBLKA, 256, 0, stream>>>(col, gHist, nE);
  k_scanA<<<NB, 256, 0, stream>>>(gHist, bTot);
  k_placeA<<<NBLKA, 256, 0, stream>>>(row, col, gHist, bTot, sorted, nE);
  k_bucketB<<<NB, 256, 0, stream>>>(sorted, bTot, cnt, start, dinv, rows, n);

  // layer 1 — PROBE: 3x (2 redundant idempotent repeats to measure C_gemm1)
  for (int rep = 0; rep < 3; ++rep)
    k_gemm1<<<gG1, BLK, 0, stream>>>(x, W1, b1, dinv, h1s, n);
  k_gather1g2<<<gWN, BLK, 0, stream>>>(rows, start, cnt, dinv, h1s, W2, b2, h2s, n);

  // layer 2 aggregation + log_softmax
  k_gather2<<<gWN, BLK, 0, stream>>>(rows, start, cnt, dinv, h2s, (float*)d_out, n);
}

// Round 10
// 458.499 us; speedup vs baseline: 2.1614x; 2.1614x over previous
//
#include <hip/hip_runtime.h>
#include <math.h>

constexpr int K_IN  = 1433;
constexpr int HID   = 16;
constexpr int NCLS  = 7;
constexpr int BLK   = 256;
constexpr int CHUNK = 256;   // K-chunk of W1 staged in LDS
constexpr int KP    = 260;   // LDS row stride (bank-spread: 260 % 32 = 4)
constexpr int NB    = 256;   // coarse buckets: bucket = col >> 9
constexpr int NBLKA = 1024;  // pass-A blocks

__device__ inline float4 wave_reduce4(float4 v) {
#pragma unroll
  for (int off = 32; off > 0; off >>= 1) {
    v.x += __shfl_xor(v.x, off);
    v.y += __shfl_xor(v.y, off);
    v.z += __shfl_xor(v.z, off);
    v.w += __shfl_xor(v.w, off);
  }
  return v;
}

// exclusive scan over 256 values held one-per-thread (256-thread block)
__device__ inline int block_excl_scan256(int v, int* wsum) {
  const int lane = threadIdx.x & 63, wid = threadIdx.x >> 6;
  int s = v;
#pragma unroll
  for (int off = 1; off < 64; off <<= 1) {
    int t = __shfl_up(s, off);
    if (lane >= off) s += t;
  }
  if (lane == 63) wsum[wid] = s;
  __syncthreads();
  int woff = 0;
#pragma unroll
  for (int k = 0; k < 4; ++k) woff += (k < wid) ? wsum[k] : 0;
  return woff + s - v;
}

// ---- atomic-free CSR build (two-level LDS-histogram counting sort) -----

__global__ __launch_bounds__(256) void k_histA(const int* __restrict__ col,
                                               int* __restrict__ gHist, int nE) {
  __shared__ int h[NB];
  h[threadIdx.x] = 0;
  __syncthreads();
  const int ch = (nE + NBLKA - 1) / NBLKA;
  const int e0 = blockIdx.x * ch;
  const int e1 = min(e0 + ch, nE);
  for (int e = e0 + threadIdx.x; e < e1; e += 256) atomicAdd(&h[col[e] >> 9], 1);
  __syncthreads();
  gHist[threadIdx.x * NBLKA + blockIdx.x] = h[threadIdx.x];  // bucket-major
}

__global__ __launch_bounds__(256) void k_scanA(int* __restrict__ gHist,
                                               int* __restrict__ bTot) {
  __shared__ int wsum[4];
  const int b = blockIdx.x, t = threadIdx.x;
  int4* p = (int4*)(gHist + (size_t)b * NBLKA);
  int4 c = p[t];
  const int tsum = c.x + c.y + c.z + c.w;
  const int base = block_excl_scan256(tsum, wsum);
  int4 o; o.x = base; o.y = base + c.x; o.z = o.y + c.y; o.w = o.z + c.z;
  p[t] = o;
  if (t == 255) bTot[b] = base + tsum;
}

__global__ __launch_bounds__(256) void k_placeA(const int* __restrict__ row,
                                                const int* __restrict__ col,
                                                const int* __restrict__ gHist,
                                                const int* __restrict__ bTot,
                                                int* __restrict__ sorted, int nE) {
  __shared__ int cur[NB];
  __shared__ int wsum[4];
  const int t = threadIdx.x;
  const int excl = block_excl_scan256(bTot[t], wsum);   // bBase on the fly
  cur[t] = excl + gHist[t * NBLKA + blockIdx.x];
  __syncthreads();
  const int ch = (nE + NBLKA - 1) / NBLKA;
  const int e0 = blockIdx.x * ch;
  const int e1 = min(e0 + ch, nE);
  for (int e = e0 + t; e < e1; e += 256) {
    const int c = col[e];
    const int p = atomicAdd(&cur[c >> 9], 1);           // LDS atomic
    sorted[p] = ((c & 511) << 17) | row[e];             // 26-bit pack
  }
}

__global__ __launch_bounds__(256) void k_bucketB(const int* __restrict__ sorted,
                                                 const int* __restrict__ bTot,
                                                 int* __restrict__ cnt,
                                                 int* __restrict__ start,
                                                 float* __restrict__ dinv,
                                                 int* __restrict__ rows, int n) {
  __shared__ int h[512];
  __shared__ int ls[512];
  __shared__ int sBase[NB];
  __shared__ int wsum[4];
  const int b = blockIdx.x, t = threadIdx.x;
  const int lane = t & 63, wid = t >> 6;
  h[t] = 0; h[t + 256] = 0;
  sBase[t] = block_excl_scan256(bTot[t], wsum);         // bBase on the fly
  __syncthreads();
  const int s0 = sBase[b];
  const int s1 = (b < 255) ? sBase[b + 1] : s0 + bTot[b];
  for (int e = s0 + t; e < s1; e += 256) atomicAdd(&h[(sorted[e] >> 17) & 511], 1);
  __syncthreads();
  const int c0 = h[2 * t], c1 = h[2 * t + 1];
  const int tsum = c0 + c1;
  int s = tsum;
#pragma unroll
  for (int off = 1; off < 64; off <<= 1) { int v = __shfl_up(s, off); if (lane >= off) s += v; }
  if (lane == 63) wsum[wid] = s;
  __syncthreads();
  int woff = 0;
#pragma unroll
  for (int k = 0; k < 4; ++k) woff += (k < wid) ? wsum[k] : 0;
  const int base = woff + s - tsum;
  ls[2 * t] = base;
  ls[2 * t + 1] = base + c0;
  const int gc0 = b * 512 + 2 * t;
  if (gc0 < n) {
    cnt[gc0] = c0; start[gc0] = s0 + base;
    dinv[gc0] = rsqrtf((float)(c0 + 1));
  }
  if (gc0 + 1 < n) {
    cnt[gc0 + 1] = c1; start[gc0 + 1] = s0 + base + c0;
    dinv[gc0 + 1] = rsqrtf((float)(c1 + 1));
  }
  __syncthreads();
  for (int e = s0 + t; e < s1; e += 256) {
    const int rc = sorted[e];
    const int p = atomicAdd(&ls[(rc >> 17) & 511], 1);  // LDS cursor
    rows[s0 + p] = rc & 0x1FFFF;
  }
}

// ---- layer compute -----------------------------------------------------

// h1s = dinv * (x @ W1 + b1). 8 rows/block, 2 rows/wave.
// v3: lane owns 4 consecutive k -> x is ONE float4 load per row per chunk;
// W staged TRANSPOSED in LDS (wt[f][k]) so W reads stay conflict-free b128.
__global__ __launch_bounds__(BLK) void k_gemm1(const float* __restrict__ x,
                                               const float* __restrict__ W1,
                                               const float* __restrict__ b1,
                                               const float* __restrict__ dinv,
                                               float* __restrict__ h1s, int n) {
  __shared__ float wt[HID][KP];   // transposed W chunk: [f][k]
  const int lane = threadIdx.x & 63;
  const int wave = threadIdx.x >> 6;
  const int r0 = blockIdx.x * 8 + wave * 2;
  const int r1 = r0 + 1;
  const bool v0 = r0 < n, v1 = r1 < n;
  const float* xr0 = x + (size_t)r0 * K_IN;
  const float* xr1 = x + (size_t)r1 * K_IN;
  float acc0[HID] = {};
  float acc1[HID] = {};

  for (int kc = 0; kc < K_IN; kc += CHUNK) {
    const int kcnt = min(CHUNK, K_IN - kc);
    // stage W1[kc..kc+kcnt) transposed: thread t -> (k = idx>>2, f-group = idx&3)
    for (int t = threadIdx.x; t < kcnt * 4; t += BLK) {
      const int kk = t >> 2, f4 = t & 3;
      const float4 v = ((const float4*)W1)[(size_t)(kc + kk) * 4 + f4];
      wt[f4 * 4 + 0][kk] = v.x;
      wt[f4 * 4 + 1][kk] = v.y;
      wt[f4 * 4 + 2][kk] = v.z;
      wt[f4 * 4 + 3][kk] = v.w;
    }
    __syncthreads();

    const int k0 = lane * 4;            // local k of this lane's quad
    float4 x0 = make_float4(0.f, 0.f, 0.f, 0.f);
    float4 x1 = make_float4(0.f, 0.f, 0.f, 0.f);
    if (kcnt == CHUNK) {                // full chunk: vectorized, in-bounds
      if (v0) x0 = *(const float4*)(xr0 + kc + k0);
      if (v1) x1 = *(const float4*)(xr1 + kc + k0);
    } else if (k0 < kcnt) {             // tail chunk: guarded scalars
      float t0[4] = {0.f, 0.f, 0.f, 0.f}, t1[4] = {0.f, 0.f, 0.f, 0.f};
#pragma unroll
      for (int i = 0; i < 4; ++i) {
        if (k0 + i < kcnt) {
          if (v0) t0[i] = xr0[kc + k0 + i];
          if (v1) t1[i] = xr1[kc + k0 + i];
        }
      }
      x0 = make_float4(t0[0], t0[1], t0[2], t0[3]);
      x1 = make_float4(t1[0], t1[1], t1[2], t1[3]);
    }
    const bool live = (k0 < kcnt);
#pragma unroll
    for (int f = 0; f < HID; ++f) {
      if (live) {
        const float4 w = *(const float4*)&wt[f][k0];
        acc0[f] = fmaf(x0.x, w.x, fmaf(x0.y, w.y, fmaf(x0.z, w.z, fmaf(x0.w, w.w, acc0[f]))));
        acc1[f] = fmaf(x1.x, w.x, fmaf(x1.y, w.y, fmaf(x1.z, w.z, fmaf(x1.w, w.w, acc1[f]))));
      }
    }
    __syncthreads();
  }

  // pack scalars into float4 and reduce across the wave
  float4 a0[4], a1[4];
#pragma unroll
  for (int f4 = 0; f4 < 4; ++f4) {
    a0[f4] = wave_reduce4(make_float4(acc0[f4 * 4], acc0[f4 * 4 + 1], acc0[f4 * 4 + 2], acc0[f4 * 4 + 3]));
    a1[f4] = wave_reduce4(make_float4(acc1[f4 * 4], acc1[f4 * 4 + 1], acc1[f4 * 4 + 2], acc1[f4 * 4 + 3]));
  }
  if (lane == 0) {
    const float4* b14 = (const float4*)b1;
    const float d0 = v0 ? dinv[r0] : 0.0f;
    const float d1 = v1 ? dinv[r1] : 0.0f;
    float4* o0 = (float4*)(h1s + (size_t)r0 * HID);
    float4* o1 = (float4*)(h1s + (size_t)r1 * HID);
#pragma unroll
    for (int f4 = 0; f4 < 4; ++f4) {
      const float4 bb = b14[f4];
      if (v0) o0[f4] = make_float4(d0 * (a0[f4].x + bb.x), d0 * (a0[f4].y + bb.y),
                                   d0 * (a0[f4].z + bb.z), d0 * (a0[f4].w + bb.w));
      if (v1) o1[f4] = make_float4(d1 * (a1[f4].x + bb.x), d1 * (a1[f4].y + bb.y),
                                   d1 * (a1[f4].z + bb.z), d1 * (a1[f4].w + bb.w));
    }
  }
}

// Fused gather-1 + gemm2: one wave per node (16 feats x 4 edge-groups).
__global__ __launch_bounds__(BLK) void k_gather1g2(const int* __restrict__ rows,
                                                   const int* __restrict__ start,
                                                   const int* __restrict__ cnt,
                                                   const float* __restrict__ dinv,
                                                   const float* __restrict__ h1s,
                                                   const float* __restrict__ W2,
                                                   const float* __restrict__ b2,
                                                   float* __restrict__ h2s, int n) {
  __shared__ float w2s[HID * NCLS];
  __shared__ float b2s[NCLS];
  if (threadIdx.x < HID * NCLS) w2s[threadIdx.x] = W2[threadIdx.x];
  if (threadIdx.x < NCLS) b2s[threadIdx.x] = b2[threadIdx.x];
  __syncthreads();
  const int node = blockIdx.x * 4 + (threadIdx.x >> 6);
  const int lane = threadIdx.x & 63;
  const int f = lane & 15;   // feature
  const int g = lane >> 4;   // edge subgroup
  if (node >= n) return;
  const float dc = dinv[node];
  float acc = (g == 0) ? h1s[(size_t)node * HID + f] : 0.0f;  // self loop
  const int m = cnt[node];
  const int* bp = rows + start[node];
  int q = g;
  for (; q + 4 < m; q += 8) {
    const int r0 = bp[q], r1 = bp[q + 4];
    acc += h1s[(size_t)r0 * HID + f];
    acc += h1s[(size_t)r1 * HID + f];
  }
  if (q < m) acc += h1s[(size_t)bp[q] * HID + f];
  acc += __shfl_xor(acc, 16);
  acc += __shfl_xor(acc, 32);
  acc = fmaxf(dc * acc, 0.0f);  // normalize + relu
  float sj[NCLS];
#pragma unroll
  for (int j = 0; j < NCLS; ++j) sj[j] = acc * w2s[f * NCLS + j];
#pragma unroll
  for (int off = 1; off < 16; off <<= 1)
#pragma unroll
    for (int j = 0; j < NCLS; ++j) sj[j] += __shfl_xor(sj[j], off);
  if (g == 0 && f < NCLS) {
    float v = sj[0];
#pragma unroll
    for (int j = 1; j < NCLS; ++j) if (f == j) v = sj[j];
    h2s[(size_t)node * NCLS + f] = dc * (v + b2s[f]);
  }
}

// gather-2 + log_softmax: one wave per node (8 feat-lanes x 8 edge-groups)
__global__ __launch_bounds__(BLK) void k_gather2(const int* __restrict__ rows,
                                                 const int* __restrict__ start,
                                                 const int* __restrict__ cnt,
                                                 const float* __restrict__ dinv,
                                                 const float* __restrict__ h2s,
                                                 float* __restrict__ out, int n) {
  const int node = blockIdx.x * 4 + (threadIdx.x >> 6);
  const int lane = threadIdx.x & 63;
  const int f = lane & 7;    // feature (f<7 active)
  const int g = lane >> 3;   // edge subgroup
  if (node >= n) return;
  const float dc = dinv[node];
  float acc = (g == 0) ? h2s[(size_t)node * NCLS + f] : 0.0f;  // self loop
  const int m = cnt[node];
  const int* bp = rows + start[node];
  int q = g;
  for (; q + 8 < m; q += 16) {
    const int r0 = bp[q], r1 = bp[q + 8];
    acc += h2s[(size_t)r0 * NCLS + f];
    acc += h2s[(size_t)r1 * NCLS + f];
  }
  if (q < m) acc += h2s[(size_t)bp[q] * NCLS + f];
  acc += __shfl_xor(acc, 8);
  acc += __shfl_xor(acc, 16);
  acc += __shfl_xor(acc, 32);
  const bool act = f < NCLS;
  const float t = fmaxf(dc * acc, 0.0f);  // normalize + relu
  float tm = act ? t : -1e30f;
#pragma unroll
  for (int off = 1; off < 8; off <<= 1) tm = fmaxf(tm, __shfl_xor(tm, off, 8));
  float se = act ? __expf(t - tm) : 0.0f;
#pragma unroll
  for (int off = 1; off < 8; off <<= 1) se += __shfl_xor(se, off, 8);
  const float lse = tm + __logf(se);
  if (g == 0 && act) out[(size_t)node * NCLS + f] = t - lse;
}

extern "C" void kernel_launch(void* const* d_in, const int* in_sizes, int n_in,
                              void* d_out, int out_size, void* d_ws, size_t ws_size,
                              hipStream_t stream) {
  const float* x  = (const float*)d_in[0];
  const float* W1 = (const float*)d_in[1];
  const float* b1 = (const float*)d_in[2];
  const float* W2 = (const float*)d_in[3];
  const float* b2 = (const float*)d_in[4];
  const int*   ei = (const int*)d_in[5];

  const int n  = in_sizes[0] / K_IN;       // 100000
  const int nE = in_sizes[5] / 2;          // 3200000
  const int* row = ei;                     // edge_index[0] (source)
  const int* col = ei + nE;                // edge_index[1] (target)

  // workspace layout, 16B-aligned blocks
  char* w = (char*)d_ws;
  size_t off = 0;
  auto alloc = [&](size_t elems) {
    void* p = w + off;
    off += ((elems * 4 + 15) & ~(size_t)15);
    return p;
  };
  int*   cnt    = (int*)alloc(n);
  int*   start  = (int*)alloc(n);
  float* dinv   = (float*)alloc(n);
  float* h1s    = (float*)alloc((size_t)n * HID);
  float* h2s    = (float*)alloc((size_t)n * NCLS + 16);  // +pad for f==7 reads
  int*   gHist  = (int*)alloc((size_t)NB * NBLKA);
  int*   bTot   = (int*)alloc(NB);
  int*   sorted = (int*)alloc(nE);
  int*   rows   = (int*)alloc(nE);

  const int gG1 = (n + 7) / 8;            // gemm1: 8 rows/block
  const int gWN = (n + 3) / 4;            // wave-per-node kernels: 4 nodes/block

  // atomic-free CSR build
  k_histA<<<NBLKA, 256, 0, stream>>>(col, gHist, nE);
  k_scanA<<<NB, 256, 0, stream>>>(gHist, bTot);
  k_placeA<<<NBLKA, 256, 0, stream>>>(row, col, gHist, bTot, sorted, nE);
  k_bucketB<<<NB, 256, 0, stream>>>(sorted, bTot, cnt, start, dinv, rows, n);

  // layer 1 (+ fused layer-2 linear)
  k_gemm1<<<gG1, BLK, 0, stream>>>(x, W1, b1, dinv, h1s, n);
  k_gather1g2<<<gWN, BLK, 0, stream>>>(rows, start, cnt, dinv, h1s, W2, b2, h2s, n);

  // layer 2 aggregation + log_softmax
  k_gather2<<<gWN, BLK, 0, stream>>>(rows, start, cnt, dinv, h2s, (float*)d_out, n);
}